// Round 6
// baseline (35.050 us; speedup 1.0000x reference)
//
#include <hip/hip_runtime.h>
#include <hip/hip_bf16.h>

// Problem dims (fixed by setup_inputs)
#define BS     256
#define N_BAG  128
#define DXD    32
#define DYD    10
#define M_COMP 2048

typedef __attribute__((ext_vector_type(8))) short short8v;   // 8 bf16 (4 VGPRs)
typedef __attribute__((ext_vector_type(4))) float f32x4;

static __device__ __forceinline__ unsigned int pkbf(float a, float b) {
    // RNE pack of two f32 -> 2x bf16 in one u32 (v_cvt_pk_bf16_f32)
    unsigned short ha = __bfloat16_as_ushort(__float2bfloat16(a));
    unsigned short hb = __bfloat16_as_ushort(__float2bfloat16(b));
    return (unsigned int)ha | ((unsigned int)hb << 16);
}
static __device__ __forceinline__ float fast_exp2(float x) {
#if __has_builtin(__builtin_amdgcn_exp2f)
    return __builtin_amdgcn_exp2f(x);
#else
    return __expf(x * 0.6931471805599453f);
#endif
}

// grid 512 = (b, m-half); block 1024 = 16 waves; 2 blocks/CU (launch_bounds(1024,8)).
// Wave-pair wp (0..7) owns 8 m-tiles; within a pair, wave 'half' owns 4 of 8 n-tiles.
// A' = (-2c2)*X bf16; seed C with c2*a2[row] + c2*b2[col] -> MFMA output == exponent.
// K^2 = 2^acc. Epilogue: exp2 + add only. b2 precomputed to LDS. Projection in phase 2.
__global__ __launch_bounds__(1024, 8) void main_kernel(
    const float* __restrict__ X,        // (BS, N_BAG, DXD)
    const float* __restrict__ sig_p,    // scalar
    const float* __restrict__ c_x,      // (M_COMP, DXD)
    const float* __restrict__ c_y,      // (M_COMP, DYD)
    const float* __restrict__ comp_w,   // (M_COMP,)
    float* __restrict__ part)           // (512, 16): [0]=wsum, [1..10]=probs partials
{
    __shared__ short8v Af[8][64];          // A' fragments, 8 n-tiles (8 KB)
    __shared__ float   a2part[N_BAG][4];
    __shared__ float   a2c[N_BAG];         // c2 * ||x_n||^2
    __shared__ float   b2c[1024];          // c2 * ||c_x[m]||^2 for this block's m's (4 KB)
    __shared__ float   ow_s[2][1024];      // per-n-half csum per m (8 KB)
    __shared__ float   red[16][12];

    const int tid   = threadIdx.x;
    const int b     = blockIdx.x >> 1;
    const int m0    = (blockIdx.x & 1) * 1024;   // this block's global m offset

    const float sgm = fmaxf(sig_p[0], 1e-3f);
    const float c2  = -1.4426950408889634f / (sgm * sgm);  // -log2(e)/sigma^2 (<0)
    const float sA  = -2.0f * c2;                          // A-side scale

    // ---- stage A' = sA*X as bf16 fragments + row norms ----
    if (tid < 512) {
        const int n = tid >> 2, g4 = tid & 3;
        const float4* Xr = (const float4*)(X + ((size_t)(b * N_BAG + n) * DXD + 8 * g4));
        float4 v0 = Xr[0], v1 = Xr[1];
        float s = 0.f;
        s = fmaf(v0.x, v0.x, s); s = fmaf(v0.y, v0.y, s);
        s = fmaf(v0.z, v0.z, s); s = fmaf(v0.w, v0.w, s);
        s = fmaf(v1.x, v1.x, s); s = fmaf(v1.y, v1.y, s);
        s = fmaf(v1.z, v1.z, s); s = fmaf(v1.w, v1.w, s);
        union { unsigned int u4[4]; short8v s8; } cv;
        cv.u4[0] = pkbf(sA * v0.x, sA * v0.y); cv.u4[1] = pkbf(sA * v0.z, sA * v0.w);
        cv.u4[2] = pkbf(sA * v1.x, sA * v1.y); cv.u4[3] = pkbf(sA * v1.z, sA * v1.w);
        Af[n >> 4][g4 * 16 + (n & 15)] = cv.s8;
        a2part[n][g4] = s;
    }
    // ---- stage c2*b2 for this block's 1024 m's ----
    {
        const float4* cp = (const float4*)(c_x + (size_t)(m0 + tid) * DXD);
        float s = 0.f;
#pragma unroll
        for (int j = 0; j < 8; ++j) {
            float4 v = cp[j];
            s = fmaf(v.x, v.x, s); s = fmaf(v.y, v.y, s);
            s = fmaf(v.z, v.z, s); s = fmaf(v.w, v.w, s);
        }
        b2c[tid] = c2 * s;
    }
    __syncthreads();
    if (tid < N_BAG)
        a2c[tid] = c2 * (a2part[tid][0] + a2part[tid][1] +
                         a2part[tid][2] + a2part[tid][3]);
    __syncthreads();

    const int lane = tid & 63, wv = tid >> 6;
    const int half = wv & 1, wp = wv >> 1;          // wave-pair 0..7, n-half 0/1
    const int r = lane & 15, gq = lane >> 4, rowg = gq * 4;

    // 4 A-fragments + 4 seed rows resident in VGPRs (one n-half)
    short8v Xf[4];
    f32x4   s4[4];
#pragma unroll
    for (int j = 0; j < 4; ++j) {
        Xf[j] = Af[half * 4 + j][lane];
        s4[j] = *(const f32x4*)&a2c[(half * 4 + j) * 16 + rowg];
    }

#pragma unroll 2
    for (int i = 0; i < 8; ++i) {
        const int ml = (wp * 8 + i) * 16 + r;       // local m (lane's C column = c_x row)
        const float4* cp4 = (const float4*)(c_x + (size_t)(m0 + ml) * DXD + 8 * gq);
        float4 p0 = cp4[0], p1 = cp4[1];
        union { unsigned int u4[4]; short8v s8; } bc;
        bc.u4[0] = pkbf(p0.x, p0.y); bc.u4[1] = pkbf(p0.z, p0.w);
        bc.u4[2] = pkbf(p1.x, p1.y); bc.u4[3] = pkbf(p1.z, p1.w);
        const float cbv = b2c[ml];                  // c2*b2[m], LDS broadcast

        float cs0 = 0.f, cs1 = 0.f, cs2 = 0.f, cs3 = 0.f;
#pragma unroll
        for (int j = 0; j < 4; ++j) {
            f32x4 seed = s4[j] + cbv;               // c2*(a2[row] + b2[col])
            f32x4 acc  = __builtin_amdgcn_mfma_f32_16x16x32_bf16(Xf[j], bc.s8, seed, 0, 0, 0);
            cs0 += fast_exp2(acc[0]); cs1 += fast_exp2(acc[1]);
            cs2 += fast_exp2(acc[2]); cs3 += fast_exp2(acc[3]);
        }
        float csum = (cs0 + cs1) + (cs2 + cs3);
        csum += __shfl_xor(csum, 16, 64);
        csum += __shfl_xor(csum, 32, 64);           // sum over this wave's 64 n-rows
        if (lane < 16) ow_s[half][ml] = csum;
    }
    __syncthreads();

    // ---- phase 2: coalesced projection over this block's 1024 m's ----
    {
        const int m = m0 + tid;
        const float w = (ow_s[0][tid] + ow_s[1][tid]) * comp_w[m] * (1.0f / N_BAG);
        const float2* cyp = (const float2*)(c_y + (size_t)m * DYD);
        float2 y0 = cyp[0], y1 = cyp[1], y2 = cyp[2], y3 = cyp[3], y4 = cyp[4];
        float cy[DYD] = {y0.x, y0.y, y1.x, y1.y, y2.x, y2.y, y3.x, y3.y, y4.x, y4.y};
        float ny = 0.f;
#pragma unroll
        for (int d = 0; d < DYD; ++d) ny = fmaf(cy[d], cy[d], ny);
        const float yw = w * __builtin_amdgcn_rcpf(ny);
        float vals[DYD + 1];
        vals[0] = w;
#pragma unroll
        for (int d = 0; d < DYD; ++d) vals[1 + d] = yw * cy[d] * cy[d];

#pragma unroll
        for (int v = 0; v <= DYD; ++v) {
            float x = vals[v];
#pragma unroll
            for (int off = 32; off > 0; off >>= 1) x += __shfl_down(x, off, 64);
            if (lane == 0) red[wv][v] = x;
        }
        __syncthreads();
        if (tid <= DYD) {
            float s = 0.f;
#pragma unroll
            for (int w16 = 0; w16 < 16; ++w16) s += red[w16][tid];
            part[(size_t)blockIdx.x * 16 + tid] = s;
        }
    }
}

// ---- combine: 256 threads; thread b merges its 2 m-half partials, normalizes ----
__global__ __launch_bounds__(256) void combine_kernel(const float* __restrict__ part,
                                                      float* __restrict__ out) {
    const int b = threadIdx.x;
    const float* p0 = part + (size_t)(2 * b) * 16;
    const float* p1 = part + (size_t)(2 * b + 1) * 16;
    float d = p0[0] + p1[0];
    d = (d == 0.f) ? 1e-16f : d;
    const float inv = 1.0f / d;
#pragma unroll
    for (int dd = 0; dd < DYD; ++dd)
        out[(size_t)b * DYD + dd] = (p0[1 + dd] + p1[1 + dd]) * inv;
}

extern "C" void kernel_launch(void* const* d_in, const int* in_sizes, int n_in,
                              void* d_out, int out_size, void* d_ws, size_t ws_size,
                              hipStream_t stream) {
    const float* X      = (const float*)d_in[0];  // (256,128,32)
    const float* sigma  = (const float*)d_in[1];  // scalar
    const float* c_x    = (const float*)d_in[2];  // (2048,32)
    const float* c_y    = (const float*)d_in[3];  // (2048,10)
    const float* comp_w = (const float*)d_in[4];  // (2048,)
    float*       out    = (float*)d_out;          // (256,10)

    float* part = (float*)d_ws;                   // 512*16 floats = 32 KB

    main_kernel<<<BS * 2, 1024, 0, stream>>>(X, sigma, c_x, c_y, comp_w, part);
    combine_kernel<<<1, 256, 0, stream>>>(part, out);
}

// Round 7
// 26.486 us; speedup vs baseline: 1.3234x; 1.3234x over previous
//
#include <hip/hip_runtime.h>
#include <hip/hip_bf16.h>

// Problem dims (fixed by setup_inputs)
#define BS     256
#define N_BAG  128
#define DXD    32
#define DYD    10
#define M_COMP 2048
#define NTILES 8              // n-tiles (128/16)
#define WAVES  16             // block = 1024 threads
#define MT_PW  8              // m-tiles per wave (128 tiles / 16 waves)

typedef __attribute__((ext_vector_type(8))) short short8v;   // 8 bf16 (4 VGPRs)
typedef __attribute__((ext_vector_type(4))) float f32x4;

static __device__ __forceinline__ unsigned int pkbf(float a, float b) {
    // RNE pack of two f32 -> 2x bf16 in one u32 (v_cvt_pk_bf16_f32)
    unsigned short ha = __bfloat16_as_ushort(__float2bfloat16(a));
    unsigned short hb = __bfloat16_as_ushort(__float2bfloat16(b));
    return (unsigned int)ha | ((unsigned int)hb << 16);
}
static __device__ __forceinline__ float fast_exp2(float x) {
#if __has_builtin(__builtin_amdgcn_exp2f)
    return __builtin_amdgcn_exp2f(x);
#else
    return __expf(x * 0.6931471805599453f);
#endif
}

// One block per batch row b; 16 waves; 1 block/CU (4 waves/SIMD, <=128 VGPR).
// Factorization: K^2 = 2^(c2*a2[n] + (-2c2)*dot) * 2^(c2*b2[m])
//   - MFMA: A' = (-2c2)*X (bf16), B = c_x (bf16), C seeded with c2*a2[row] only.
//   - per-element epilogue: exp2 + add. NOTHING else in the hot loop.
//   - 2^(c2*b2[m]) * comp_w[m]/N precomputed per block into LDS (ebw), applied in phase 2.
__global__ __launch_bounds__(1024, 4) void fused_kernel(
    const float* __restrict__ X,        // (BS, N_BAG, DXD)
    const float* __restrict__ sig_p,    // scalar
    const float* __restrict__ c_x,      // (M_COMP, DXD)
    const float* __restrict__ c_y,      // (M_COMP, DYD)
    const float* __restrict__ comp_w,   // (M_COMP,)
    float* __restrict__ out)            // (BS, DYD)
{
    __shared__ short8v Af[NTILES][64];     // A' fragments (8 KB)
    __shared__ float   a2part[N_BAG][4];
    __shared__ float   a2c[N_BAG];         // c2 * ||x_n||^2
    __shared__ float   ebw[M_COMP];        // 2^(c2*b2[m]) * comp_w[m] / N  (8 KB)
    __shared__ float   ow_s[M_COMP];       // sum_n 2^acc per m (8 KB)
    __shared__ float   red[WAVES][12];
    __shared__ float   sm[12];

    const int tid = threadIdx.x;
    const int b   = blockIdx.x;

    const float sgm = fmaxf(sig_p[0], 1e-3f);
    const float c2  = -1.4426950408889634f / (sgm * sgm);  // -log2(e)/sigma^2 (<0)
    const float sA  = -2.0f * c2;                          // A-side scale (>0)

    // ---- stage A' = sA*X as bf16 fragments + row norms (threads 0..511) ----
    if (tid < 512) {
        const int n = tid >> 2, g4 = tid & 3;
        const float4* Xr = (const float4*)(X + ((size_t)(b * N_BAG + n) * DXD + 8 * g4));
        float4 v0 = Xr[0], v1 = Xr[1];
        float s = 0.f;
        s = fmaf(v0.x, v0.x, s); s = fmaf(v0.y, v0.y, s);
        s = fmaf(v0.z, v0.z, s); s = fmaf(v0.w, v0.w, s);
        s = fmaf(v1.x, v1.x, s); s = fmaf(v1.y, v1.y, s);
        s = fmaf(v1.z, v1.z, s); s = fmaf(v1.w, v1.w, s);
        union { unsigned int u4[4]; short8v s8; } cv;
        cv.u4[0] = pkbf(sA * v0.x, sA * v0.y); cv.u4[1] = pkbf(sA * v0.z, sA * v0.w);
        cv.u4[2] = pkbf(sA * v1.x, sA * v1.y); cv.u4[3] = pkbf(sA * v1.z, sA * v1.w);
        Af[n >> 4][g4 * 16 + (n & 15)] = cv.s8;
        a2part[n][g4] = s;
    }
    // ---- stage ebw[m] = 2^(c2*||c_x[m]||^2) * comp_w[m]/N for all 2048 m (all threads) ----
#pragma unroll
    for (int k = 0; k < 2; ++k) {
        const int m = tid + 1024 * k;
        const float4* cp = (const float4*)(c_x + (size_t)m * DXD);
        float s = 0.f;
#pragma unroll
        for (int j = 0; j < 8; ++j) {
            float4 v = cp[j];
            s = fmaf(v.x, v.x, s); s = fmaf(v.y, v.y, s);
            s = fmaf(v.z, v.z, s); s = fmaf(v.w, v.w, s);
        }
        ebw[m] = fast_exp2(c2 * s) * comp_w[m] * (1.0f / N_BAG);
    }
    __syncthreads();
    if (tid < N_BAG)
        a2c[tid] = c2 * (a2part[tid][0] + a2part[tid][1] +
                         a2part[tid][2] + a2part[tid][3]);
    __syncthreads();

    // ---- per-wave register state: 8 A-frags + 8 seed rows (64 VGPR) ----
    const int lane = tid & 63, wv = tid >> 6;
    const int r = lane & 15, gq = lane >> 4, rowg = gq * 4;
    short8v Ah[NTILES];
    f32x4   a2f[NTILES];
#pragma unroll
    for (int t = 0; t < NTILES; ++t) {
        Ah[t]  = Af[t][lane];
        a2f[t] = *(const f32x4*)&a2c[t * 16 + rowg];
    }

    const int    m_base = wv * (MT_PW * 16) + r;    // m for tile i = m_base + 16*i
    const float* cxp    = c_x + (size_t)m_base * DXD + 8 * gq;

    float4 p0 = *(const float4*)(cxp);
    float4 p1 = *(const float4*)(cxp + 4);

#pragma unroll
    for (int i = 0; i < MT_PW; ++i) {
        // prefetch next c_x tile (static predicate under full unroll)
        float4 q0, q1;
        if (i + 1 < MT_PW) {
            q0 = *(const float4*)(cxp + (i + 1) * 16 * DXD);
            q1 = *(const float4*)(cxp + (i + 1) * 16 * DXD + 4);
        }
        union { unsigned int u4[4]; short8v s8; } bc;
        bc.u4[0] = pkbf(p0.x, p0.y); bc.u4[1] = pkbf(p0.z, p0.w);
        bc.u4[2] = pkbf(p1.x, p1.y); bc.u4[3] = pkbf(p1.z, p1.w);

        float cs0 = 0.f, cs1 = 0.f, cs2 = 0.f, cs3 = 0.f;
#pragma unroll
        for (int t = 0; t < NTILES; ++t) {
            f32x4 acc = __builtin_amdgcn_mfma_f32_16x16x32_bf16(Ah[t], bc.s8, a2f[t], 0, 0, 0);
            cs0 += fast_exp2(acc[0]); cs1 += fast_exp2(acc[1]);
            cs2 += fast_exp2(acc[2]); cs3 += fast_exp2(acc[3]);
        }
        float csum = (cs0 + cs1) + (cs2 + cs3);
        csum += __shfl_xor(csum, 16, 64);
        csum += __shfl_xor(csum, 32, 64);           // sum over all 128 n
        if (lane < 16) ow_s[m_base + 16 * i] = csum;
        p0 = q0; p1 = q1;
    }
    __syncthreads();

    // ---- phase 2: coalesced projection over all 2048 m's; block-reduce; write out ----
    float vals[DYD + 1];
#pragma unroll
    for (int v = 0; v <= DYD; ++v) vals[v] = 0.f;
#pragma unroll
    for (int k = 0; k < 2; ++k) {
        const int m = tid + 1024 * k;
        const float w = ow_s[m] * ebw[m];
        const float2* cyp = (const float2*)(c_y + (size_t)m * DYD);
        float2 y0 = cyp[0], y1 = cyp[1], y2 = cyp[2], y3 = cyp[3], y4 = cyp[4];
        float cy[DYD] = {y0.x, y0.y, y1.x, y1.y, y2.x, y2.y, y3.x, y3.y, y4.x, y4.y};
        float ny = 0.f;
#pragma unroll
        for (int d = 0; d < DYD; ++d) ny = fmaf(cy[d], cy[d], ny);
        const float yw = w * __builtin_amdgcn_rcpf(ny);
        vals[0] += w;
#pragma unroll
        for (int d = 0; d < DYD; ++d) vals[1 + d] = fmaf(yw, cy[d] * cy[d], vals[1 + d]);
    }
#pragma unroll
    for (int v = 0; v <= DYD; ++v) {
        float x = vals[v];
#pragma unroll
        for (int off = 32; off > 0; off >>= 1) x += __shfl_down(x, off, 64);
        if (lane == 0) red[wv][v] = x;
    }
    __syncthreads();
    if (tid <= DYD) {
        float s = 0.f;
#pragma unroll
        for (int w16 = 0; w16 < WAVES; ++w16) s += red[w16][tid];
        sm[tid] = s;
    }
    __syncthreads();
    if (tid < DYD) {
        float d = sm[0];
        d = (d == 0.f) ? 1e-16f : d;
        out[(size_t)b * DYD + tid] = sm[1 + tid] / d;
    }
}

extern "C" void kernel_launch(void* const* d_in, const int* in_sizes, int n_in,
                              void* d_out, int out_size, void* d_ws, size_t ws_size,
                              hipStream_t stream) {
    const float* X      = (const float*)d_in[0];  // (256,128,32)
    const float* sigma  = (const float*)d_in[1];  // scalar
    const float* c_x    = (const float*)d_in[2];  // (2048,32)
    const float* c_y    = (const float*)d_in[3];  // (2048,10)
    const float* comp_w = (const float*)d_in[4];  // (2048,)
    float*       out    = (float*)d_out;          // (256,10)

    fused_kernel<<<BS, 1024, 0, stream>>>(X, sigma, c_x, c_y, comp_w, out);
}